// Round 7
// baseline (193.085 us; speedup 1.0000x reference)
//
#include <hip/hip_runtime.h>
#include <hip/hip_bf16.h>

#define BATCH   64
#define C_IN    512
#define C_OUT   512
#define SPATIAL 784          // 28*28
#define KSMALL  256          // K = C_OUT * 0.5
#define RATE    0.5f

// ---------------------------------------------------------------------------
// Kernel 1: s[b][c] = mean(|x[b,c,:,:]|).  FOUR pairs per wave (R4 was 1:
// 12 loads then a dependent reduce -> bubble-bound, ~3x off BW peak).
// 48 float4 loads in flight per wave; 4 independent butterflies; one
// float4 store.  2048 blocks x 256 threads.
// ---------------------------------------------------------------------------
__global__ __launch_bounds__(256) void absmean_kernel(const float* __restrict__ x,
                                                      float* __restrict__ s) {
    const int gwave = (blockIdx.x * blockDim.x + threadIdx.x) >> 6;  // 0..8191
    const int lane  = threadIdx.x & 63;
    const int p0    = gwave * 4;                  // first of 4 pairs

    const float4* base = reinterpret_cast<const float4*>(x) + (size_t)p0 * 196;
    float acc[4] = {0.f, 0.f, 0.f, 0.f};
#pragma unroll
    for (int j = 0; j < 3; ++j) {                 // 192 float4 per pair
#pragma unroll
        for (int p = 0; p < 4; ++p) {
            float4 v = base[p * 196 + lane + 64 * j];
            acc[p] += fabsf(v.x) + fabsf(v.y) + fabsf(v.z) + fabsf(v.w);
        }
    }
    if (lane < 4) {                               // tail 4 float4 per pair
#pragma unroll
        for (int p = 0; p < 4; ++p) {
            float4 v = base[p * 196 + 192 + lane];
            acc[p] += fabsf(v.x) + fabsf(v.y) + fabsf(v.z) + fabsf(v.w);
        }
    }
#pragma unroll
    for (int off = 32; off; off >>= 1) {
#pragma unroll
        for (int p = 0; p < 4; ++p) acc[p] += __shfl_xor(acc[p], off);
    }
    if (lane == 0) {
        float4 r;
        r.x = acc[0] * (1.0f / SPATIAL);
        r.y = acc[1] * (1.0f / SPATIAL);
        r.z = acc[2] * (1.0f / SPATIAL);
        r.w = acc[3] * (1.0f / SPATIAL);
        *reinterpret_cast<float4*>(s + p0) = r;
    }
}

// ---------------------------------------------------------------------------
// Kernel 2 (fused): per batch row -- gate GEMV + relu + stable-rank top-K
// zeroing + renorm.  One block (512 thr) per row; no g global roundtrip.
// GEMV: 8-lane groups each own one output; 8 outputs/wave in parallel
// (kills R2's 6-deep wave-wide shfl chain).  W rows are L2-resident
// (1.05 MB shared by all 64 blocks); s broadcast from LDS conflict-free.
// Stable rank reproduces lax.top_k(-g,K) tie-break (absmax 0.0 R2-R4).
// ---------------------------------------------------------------------------
__global__ __launch_bounds__(512) void gate_kernel(const float* __restrict__ s,
                                                   const float* __restrict__ W,
                                                   const float* __restrict__ bias,
                                                   float* __restrict__ out) {
    const int b    = blockIdx.x;
    const int t    = threadIdx.x;        // 0..511
    const int lane = t & 63;
    const int wid  = t >> 6;             // 0..7
    const int l    = lane & 7;           // lane within 8-lane group
    const int grp  = lane >> 3;          // output group 0..7

    __shared__ float sh_s[C_IN];
    __shared__ float sh_g[C_OUT];
    __shared__ float sh_red[8];

    sh_s[t] = s[b * C_IN + t];
    __syncthreads();

    // 8 outer iterations x 8 waves x 8 groups = 512 outputs
#pragma unroll 2
    for (int it = 0; it < 8; ++it) {
        const int c = it * 64 + wid * 8 + grp;
        const float* wr = W + (size_t)c * (C_IN + 1);
        float a = 0.0f;
#pragma unroll 16
        for (int k = 0; k < 64; ++k) {           // j = l + 8k covers 0..511
            const int j = l + 8 * k;
            a += wr[j] * sh_s[j];
        }
        if (l == 0) a += RATE * wr[C_IN];        // rate column (j = 512)
        a += __shfl_xor(a, 1);
        a += __shfl_xor(a, 2);
        a += __shfl_xor(a, 4);
        if (l == 0) sh_g[c] = fmaxf(a + bias[c], 0.0f);
    }
    __syncthreads();

    // stable rank of this thread's element among the row
    const float gv = sh_g[t];
    const float4* shv = reinterpret_cast<const float4*>(sh_g);
    int rank = 0;
#pragma unroll 8
    for (int j4 = 0; j4 < C_OUT / 4; ++j4) {
        const float4 v = shv[j4];
        const int j = j4 * 4;
        rank += (v.x < gv) | ((v.x == gv) & (j + 0 < t));
        rank += (v.y < gv) | ((v.y == gv) & (j + 1 < t));
        rank += (v.z < gv) | ((v.z == gv) & (j + 2 < t));
        rank += (v.w < gv) | ((v.w == gv) & (j + 3 < t));
    }
    const float kept = (rank >= KSMALL) ? gv : 0.0f;

    float sum = kept;
#pragma unroll
    for (int off = 32; off; off >>= 1) sum += __shfl_xor(sum, off);
    if (lane == 0) sh_red[wid] = sum;
    __syncthreads();
    if (t == 0) {
        float tot = 0.0f;
#pragma unroll
        for (int w = 0; w < 8; ++w) tot += sh_red[w];
        sh_red[0] = tot;
    }
    __syncthreads();

    out[b * C_OUT + t] = kept * ((float)C_OUT / sh_red[0]);
}

// ---------------------------------------------------------------------------
extern "C" void kernel_launch(void* const* d_in, const int* in_sizes, int n_in,
                              void* d_out, int out_size, void* d_ws, size_t ws_size,
                              hipStream_t stream) {
    const float* x    = (const float*)d_in[0];   // [64,512,28,28]
    const float* W    = (const float*)d_in[1];   // [512,513]
    const float* bias = (const float*)d_in[2];   // [512]
    float* out        = (float*)d_out;           // [64,512] (x1x1)
    float* s          = (float*)d_ws;            // [64,512] scratch

    // Phase 1: abs-mean. 8192 waves x 4 pairs each.
    absmean_kernel<<<2048, 256, 0, stream>>>(x, s);

    // Phase 2: fused gate GEMV + topK + renorm. One block per batch row.
    gate_kernel<<<BATCH, 512, 0, stream>>>(s, W, bias, out);
}

// Round 8
// 175.419 us; speedup vs baseline: 1.1007x; 1.1007x over previous
//
#include <hip/hip_runtime.h>
#include <hip/hip_bf16.h>

#define BATCH   64
#define C_IN    512
#define C_OUT   512
#define SPATIAL 784          // 28*28
#define KSMALL  256          // K = C_OUT * 0.5
#define RATE    0.5f

// ---------------------------------------------------------------------------
// Kernel 1: s[b][c] = mean(|x[b,c,:,:]|).  FOUR pairs per wave, 48 float4
// loads in flight, 4 independent butterflies, one float4 store.
// (Kept from R7 — the accounting says this piece improved ~12us.)
// ---------------------------------------------------------------------------
__global__ __launch_bounds__(256) void absmean_kernel(const float* __restrict__ x,
                                                      float* __restrict__ s) {
    const int gwave = (blockIdx.x * blockDim.x + threadIdx.x) >> 6;  // 0..8191
    const int lane  = threadIdx.x & 63;
    const int p0    = gwave * 4;                  // first of 4 pairs

    const float4* base = reinterpret_cast<const float4*>(x) + (size_t)p0 * 196;
    float acc[4] = {0.f, 0.f, 0.f, 0.f};
#pragma unroll
    for (int j = 0; j < 3; ++j) {                 // 192 float4 per pair
#pragma unroll
        for (int p = 0; p < 4; ++p) {
            float4 v = base[p * 196 + lane + 64 * j];
            acc[p] += fabsf(v.x) + fabsf(v.y) + fabsf(v.z) + fabsf(v.w);
        }
    }
    if (lane < 4) {                               // tail 4 float4 per pair
#pragma unroll
        for (int p = 0; p < 4; ++p) {
            float4 v = base[p * 196 + 192 + lane];
            acc[p] += fabsf(v.x) + fabsf(v.y) + fabsf(v.z) + fabsf(v.w);
        }
    }
#pragma unroll
    for (int off = 32; off; off >>= 1) {
#pragma unroll
        for (int p = 0; p < 4; ++p) acc[p] += __shfl_xor(acc[p], off);
    }
    if (lane == 0) {
        float4 r;
        r.x = acc[0] * (1.0f / SPATIAL);
        r.y = acc[1] * (1.0f / SPATIAL);
        r.z = acc[2] * (1.0f / SPATIAL);
        r.w = acc[3] * (1.0f / SPATIAL);
        *reinterpret_cast<float4*>(s + p0) = r;
    }
}

// ---------------------------------------------------------------------------
// Kernel 2: gate GEMV, 4 outputs per wave, 2048 blocks (full chip).
// REVERTED to the R3-measured structure: R7's fused 64-block gate kernel
// regressed +32us (513-deep serial FMA chain, 2 waves/CU — same disease as
// R2's 72us kernel).  Launch-width beats fusion here.
// ---------------------------------------------------------------------------
__global__ __launch_bounds__(256) void gemv_kernel(const float* __restrict__ s,
                                                   const float* __restrict__ W,
                                                   const float* __restrict__ bias,
                                                   float* __restrict__ g) {
    const int gwave = (blockIdx.x * blockDim.x + threadIdx.x) >> 6;  // 0..8191
    const int lane  = threadIdx.x & 63;
    const int b  = gwave >> 7;               // / 128 waves per batch row
    const int c0 = (gwave & 127) * 4;        // 4 consecutive outputs

    const float* sr = s + b * C_IN;
    float s_reg[8];
#pragma unroll
    for (int j = 0; j < 8; ++j) s_reg[j] = sr[lane + 64 * j];

    float acc[4];
#pragma unroll
    for (int o = 0; o < 4; ++o) {
        const float* wr = W + (size_t)(c0 + o) * (C_IN + 1);
        float a = 0.0f;
#pragma unroll
        for (int j = 0; j < 8; ++j) a += wr[lane + 64 * j] * s_reg[j];
        if (lane == 0) a += RATE * wr[C_IN];         // rate column
        acc[o] = a;
    }
#pragma unroll
    for (int off = 32; off; off >>= 1) {
#pragma unroll
        for (int o = 0; o < 4; ++o) acc[o] += __shfl_xor(acc[o], off);
    }
    if (lane == 0) {
        float4 r;
        r.x = fmaxf(acc[0] + bias[c0 + 0], 0.0f);
        r.y = fmaxf(acc[1] + bias[c0 + 1], 0.0f);
        r.z = fmaxf(acc[2] + bias[c0 + 2], 0.0f);
        r.w = fmaxf(acc[3] + bias[c0 + 3], 0.0f);
        *reinterpret_cast<float4*>(g + b * C_OUT + c0) = r;
    }
}

// ---------------------------------------------------------------------------
// Kernel 3: per batch row -- stable-rank top-K-smallest zeroing + renorm.
// rank = #{g_j < g_t} + #{j<t : g_j == g_t} reproduces lax.top_k(-g,K)
// lower-index-first tie-break exactly (absmax 0.0 in R2-R4, R7).
// ---------------------------------------------------------------------------
__global__ __launch_bounds__(512) void topk_kernel(const float* __restrict__ g,
                                                   float* __restrict__ out) {
    const int b    = blockIdx.x;
    const int t    = threadIdx.x;        // 0..511
    const int lane = t & 63;
    const int wid  = t >> 6;

    __shared__ float sh_g[C_OUT];
    __shared__ float sh_red[8];

    const float gv = g[b * C_OUT + t];
    sh_g[t] = gv;
    __syncthreads();

    const float4* shv = reinterpret_cast<const float4*>(sh_g);
    int rank = 0;
#pragma unroll 8
    for (int j4 = 0; j4 < C_OUT / 4; ++j4) {
        const float4 v = shv[j4];
        const int j = j4 * 4;
        rank += (v.x < gv) | ((v.x == gv) & (j + 0 < t));
        rank += (v.y < gv) | ((v.y == gv) & (j + 1 < t));
        rank += (v.z < gv) | ((v.z == gv) & (j + 2 < t));
        rank += (v.w < gv) | ((v.w == gv) & (j + 3 < t));
    }
    const float kept = (rank >= KSMALL) ? gv : 0.0f;

    float sum = kept;
#pragma unroll
    for (int off = 32; off; off >>= 1) sum += __shfl_xor(sum, off);
    if (lane == 0) sh_red[wid] = sum;
    __syncthreads();
    if (t == 0) {
        float tot = 0.0f;
#pragma unroll
        for (int w = 0; w < 8; ++w) tot += sh_red[w];
        sh_red[0] = tot;
    }
    __syncthreads();

    out[b * C_OUT + t] = kept * ((float)C_OUT / sh_red[0]);
}

// ---------------------------------------------------------------------------
extern "C" void kernel_launch(void* const* d_in, const int* in_sizes, int n_in,
                              void* d_out, int out_size, void* d_ws, size_t ws_size,
                              hipStream_t stream) {
    const float* x    = (const float*)d_in[0];   // [64,512,28,28]
    const float* W    = (const float*)d_in[1];   // [512,513]
    const float* bias = (const float*)d_in[2];   // [512]
    float* out        = (float*)d_out;           // [64,512] (x1x1)
    float* s          = (float*)d_ws;                        // [64,512]
    float* g          = (float*)d_ws + BATCH * C_IN;         // [64,512]

    // Phase 1: abs-mean. 8192 waves x 4 pairs each. 2048 blocks.
    absmean_kernel<<<2048, 256, 0, stream>>>(x, s);

    // Phase 2: GEMV, 4 outputs per wave. 2048 blocks.
    gemv_kernel<<<BATCH * C_OUT / 16, 256, 0, stream>>>(s, W, bias, g);

    // Phase 3: top-K zero + renormalize. One block per batch row.
    topk_kernel<<<BATCH, 512, 0, stream>>>(g, out);
}